// Round 5
// baseline (359.598 us; speedup 1.0000x reference)
//
#include <hip/hip_runtime.h>
#include <hip/hip_bf16.h>
#include <math.h>

#define KN 64
#define HO 124
#define KP 104
#define NOUT (128LL * 124 * 124 * 64)  // 125,960,192
#define NG 31                          // 124/4 ho-groups per image

typedef short bfrag8 __attribute__((ext_vector_type(8)));  // 8 bf16
typedef float ffrag4 __attribute__((ext_vector_type(4)));  // 4 f32

// ws layout (big path): X4 64 MB | cs 8 MB | w_bf 13312 B | sp 256 B
#define WS_X_OFF 0
#define WS_CS_OFF 67108864ULL
#define WS_WBF_OFF (WS_CS_OFF + 8388608ULL)
#define WS_SP_OFF (WS_WBF_OFF + 13312ULL)
#define WS_NEED (WS_SP_OFF + 256ULL)

// round-to-nearest-even f32 -> bf16 bits (finite inputs)
__device__ __forceinline__ unsigned short f2bf(float f) {
    union { float f; unsigned u; } x;
    x.f = f;
    unsigned r = x.u + 0x7fffu + ((x.u >> 16) & 1u);
    return (unsigned short)(r >> 16);
}
__device__ __forceinline__ unsigned pack2(float a, float b) {
    return (unsigned)f2bf(a) | ((unsigned)f2bf(b) << 16);
}

// ---------------- one-time prep: weight transpose->bf16 + softplus ---------
__global__ void prep_kernel(const float* __restrict__ w_mu,
                            const float* __restrict__ w_sigma,
                            unsigned short* __restrict__ w_bf,
                            float* __restrict__ sp_out) {
    const int tid = threadIdx.x;       // 256
    const int n = tid >> 2;            // 64 rows, 4 threads each
    const int kbase = (tid & 3) * 26;  // 4*26 = 104
#pragma unroll
    for (int kk = 0; kk < 26; ++kk) {
        const int k = kbase + kk;
        float v = 0.f;
        if (k < 80) {
            const int r = k >> 4, t = k & 15;
            if (t < 15) v = w_mu[(r * 15 + t) * KN + n];
        }
        w_bf[n * KP + k] = f2bf(v);
    }
    if (tid < KN) sp_out[tid] = log1pf(expf(w_sigma[tid]));
}

// ---------------- KL scalar kernel (one wave) ----------------
__global__ void kl_kernel(const float* __restrict__ w_mu,
                          const float* __restrict__ w_sigma,
                          float* __restrict__ out_kl) {
    int kn = threadIdx.x;  // 64 threads
    float s = 0.f;
#pragma unroll
    for (int i = 0; i < 75; ++i) {
        float m = w_mu[i * KN + kn];
        s = fmaf(m, m, s);
    }
    float lv = w_sigma[kn];
    float sp = log1pf(expf(lv));
    float val = 1.0f + lv - sp - s * (1.0f / 75.0f);
#pragma unroll
    for (int off = 32; off > 0; off >>= 1) val += __shfl_down(val, off);
    if (kn == 0) {
        float kl = -(val / 64.0f);
        if (isnan(kl) || isinf(kl)) kl = 1e-5f;
        out_kl[0] = kl;
    }
}

// ============ BIG-WS PATH ============
// Prepass: per (b,h) row, build swizzled bf16 im2col chunks + channel sum-sq.
// Chunk (wo, half) holds bf16 values t = half*8 + j, j=0..7 (t=dc*3+c, t=15=0),
// stored at chunk index c = wo*2 + (half ^ ((wo>>2)&1))  (bank swizzle).
__global__ void x_build_kernel(const float* __restrict__ mu_in,
                               uint4* __restrict__ X4,
                               float* __restrict__ cs_ws) {
    __shared__ __align__(16) float s_row[384];
    const int bh = blockIdx.x;  // 0 .. 16383
    const int tid = threadIdx.x;
    const float* src = mu_in + (size_t)bh * 384;
    if (tid < 96)
        reinterpret_cast<float4*>(s_row)[tid] =
            reinterpret_cast<const float4*>(src)[tid];
    __syncthreads();
    if (tid < 128) {
        float a = s_row[3 * tid], b2 = s_row[3 * tid + 1],
              c2 = s_row[3 * tid + 2];
        cs_ws[(size_t)bh * 128 + tid] = a * a + b2 * b2 + c2 * c2;
    }
    const int wo = tid >> 1, half = tid & 1;
    unsigned u[4];
#pragma unroll
    for (int p = 0; p < 4; ++p) {
        const int t0 = half * 8 + 2 * p, t1 = t0 + 1;
        float v0 = 0.f, v1 = 0.f;
        if (wo < 124) {
            v0 = (t0 < 15) ? s_row[wo * 3 + t0] : 0.f;
            v1 = (t1 < 15) ? s_row[wo * 3 + t1] : 0.f;
        }
        u[p] = pack2(v0, v1);
    }
    const int c = wo * 2 + (half ^ ((wo >> 2) & 1));
    X4[(size_t)bh * 256 + c] = make_uint4(u[0], u[1], u[2], u[3]);
}

// Lean conv: stage pre-built X chunks + cs (pure vector copies), ssn reduce,
// 96 MFMA, nontemporal stores. No conversions, no spills.
__global__ __launch_bounds__(256, 4) void conv2_kernel(
    const uint4* __restrict__ X4, const float* __restrict__ cs_ws,
    const unsigned short* __restrict__ w_bf, const float* __restrict__ sp_in,
    float* __restrict__ mu_out, float* __restrict__ sig_out) {

    __shared__ __align__(16) unsigned short s_im[8 * 128 * 16];  // 32 KB
    __shared__ __align__(16) float s_cs[8 * 128];                // 4 KB
    __shared__ float s_ssn[4 * 128];                             // 2 KB
    __shared__ float s_sp[KN];

    const int bid = blockIdx.x;
    const int b = bid / NG;
    const int h0 = (bid % NG) * 4;
    const int tid = threadIdx.x;
    const int lane = tid & 63;
    const int wid = tid >> 6;
    const int llo = lane & 15;
    const int lhi = lane >> 4;

    // stage X tile (8 rows x 256 chunks) + cs tile, fully coalesced
    {
        const uint4* xs = X4 + (size_t)(b * 128 + h0) * 256;
        uint4* d = reinterpret_cast<uint4*>(s_im);
#pragma unroll
        for (int i = 0; i < 8; ++i) d[tid + i * 256] = xs[tid + i * 256];
        reinterpret_cast<uint4*>(s_cs)[tid] = reinterpret_cast<const uint4*>(
            cs_ws + (size_t)(b * 128 + h0) * 128)[tid];
    }
    // weights -> regs (L2-hot), softplus -> LDS
    bfrag8 afr[4][3];
#pragma unroll
    for (int mt = 0; mt < 4; ++mt)
#pragma unroll
        for (int ks = 0; ks < 3; ++ks)
            afr[mt][ks] = *reinterpret_cast<const bfrag8*>(
                &w_bf[(mt * 16 + llo) * KP + ks * 32 + lhi * 8]);
    if (tid < KN) s_sp[tid] = sp_in[tid];
    __syncthreads();

    // ssn[hl][wo] = (5x5 window sum of cs) / 75
#pragma unroll
    for (int it = 0; it < 2; ++it) {
        const int idx = tid + it * 256;
        const int hl = idx >> 7, wo = idx & 127;
        float v = 0.f;
        if (wo < HO) {
            float s = 0.f;
#pragma unroll
            for (int r = 0; r < 5; ++r) {
                const float* cr = &s_cs[(hl + r) * 128 + wo];
                s += cr[0] + cr[1] + cr[2] + cr[3] + cr[4];
            }
            v = s * (1.0f / 75.0f);
        }
        s_ssn[idx] = v;
    }
    __syncthreads();

    float4 sp4[4];
#pragma unroll
    for (int mt = 0; mt < 4; ++mt)
        sp4[mt] = *reinterpret_cast<const float4*>(&s_sp[mt * 16 + lhi * 4]);

    const uint4* sim4 = reinterpret_cast<const uint4*>(s_im);
#pragma unroll
    for (int hl = 0; hl < 4; ++hl) {
        ffrag4 acc[2][4];
#pragma unroll
        for (int nt = 0; nt < 2; ++nt)
#pragma unroll
            for (int mt = 0; mt < 4; ++mt)
                acc[nt][mt] = (ffrag4){0.f, 0.f, 0.f, 0.f};

#pragma unroll
        for (int nt = 0; nt < 2; ++nt) {
            const int wo = (wid * 2 + nt) * 16 + llo;
            const int swz = (lhi & 1) ^ ((wo >> 2) & 1);
#pragma unroll
            for (int ks = 0; ks < 3; ++ks) {
                const int rk = 2 * ks + (lhi >> 1);  // 5 => k>=80: zero operand
                bfrag8 bfr = (bfrag8){0, 0, 0, 0, 0, 0, 0, 0};
                if (rk < 5)
                    bfr = *reinterpret_cast<const bfrag8*>(
                        &sim4[(hl + rk) * 256 + wo * 2 + swz]);
#pragma unroll
                for (int mt = 0; mt < 4; ++mt)
                    acc[nt][mt] = __builtin_amdgcn_mfma_f32_16x16x32_bf16(
                        afr[mt][ks], bfr, acc[nt][mt], 0, 0, 0);
            }
        }

        const size_t orow = (size_t)(b * HO + h0 + hl) * (size_t)(HO * KN);
#pragma unroll
        for (int nt = 0; nt < 2; ++nt) {
            const int wo = (wid * 2 + nt) * 16 + llo;
            if (wo < HO) {
                const float ssn = s_ssn[hl * 128 + wo];
                float* mp = mu_out + orow + (size_t)wo * KN;
                float* gp = sig_out + orow + (size_t)wo * KN;
#pragma unroll
                for (int mt = 0; mt < 4; ++mt) {
                    const int knb = mt * 16 + lhi * 4;
                    ffrag4 sv = {sp4[mt].x * ssn, sp4[mt].y * ssn,
                                 sp4[mt].z * ssn, sp4[mt].w * ssn};
                    __builtin_nontemporal_store(acc[nt][mt],
                                                (ffrag4*)(mp + knb));
                    __builtin_nontemporal_store(sv, (ffrag4*)(gp + knb));
                }
            }
        }
    }
}

// ============ FALLBACK PATH (R4, known-good 242 us) ============
__device__ __forceinline__ int im_off(int row, int wo, int half) {
    return (((row * 128 + wo) * 32) + half * 16) ^ (((wo >> 2) & 7) << 4);
}

template <int OFF>
__device__ __forceinline__ void im_fill(const float* __restrict__ mu_in,
                                        unsigned short* s_im, int b, int ho0,
                                        int lane, int wo) {
#pragma unroll
    for (int j = 0; j < 4; ++j) {
        const int row = ((lane >> 5) << 2) + j;  // 0..7
        uint4* dst0 =
            reinterpret_cast<uint4*>((char*)s_im + im_off(row, wo, 0));
        uint4* dst1 =
            reinterpret_cast<uint4*>((char*)s_im + im_off(row, wo, 1));
        if (wo >= 124) {
            *dst0 = make_uint4(0u, 0u, 0u, 0u);
            *dst1 = make_uint4(0u, 0u, 0u, 0u);
            continue;
        }
        const float* p =
            mu_in + ((size_t)(b * 128 + ho0 + row) * 384 + wo * 3 - OFF);
        float w[20];
        float4 f;
        f = reinterpret_cast<const float4*>(p)[0];
        w[0] = f.x; w[1] = f.y; w[2] = f.z; w[3] = f.w;
        f = reinterpret_cast<const float4*>(p)[1];
        w[4] = f.x; w[5] = f.y; w[6] = f.z; w[7] = f.w;
        f = reinterpret_cast<const float4*>(p)[2];
        w[8] = f.x; w[9] = f.y; w[10] = f.z; w[11] = f.w;
        f = reinterpret_cast<const float4*>(p)[3];
        w[12] = f.x; w[13] = f.y; w[14] = f.z; w[15] = f.w;
        if (OFF >= 2) {
            f = reinterpret_cast<const float4*>(p)[4];
            w[16] = f.x; w[17] = f.y; w[18] = f.z; w[19] = f.w;
        } else {
            w[16] = 0.f; w[17] = 0.f; w[18] = 0.f; w[19] = 0.f;
        }
        unsigned u0 = pack2(w[OFF + 0], w[OFF + 1]);
        unsigned u1 = pack2(w[OFF + 2], w[OFF + 3]);
        unsigned u2 = pack2(w[OFF + 4], w[OFF + 5]);
        unsigned u3 = pack2(w[OFF + 6], w[OFF + 7]);
        unsigned u4 = pack2(w[OFF + 8], w[OFF + 9]);
        unsigned u5 = pack2(w[OFF + 10], w[OFF + 11]);
        unsigned u6 = pack2(w[OFF + 12], w[OFF + 13]);
        unsigned u7 = pack2(w[OFF + 14], 0.0f);
        *dst0 = make_uint4(u0, u1, u2, u3);
        *dst1 = make_uint4(u4, u5, u6, u7);
    }
}

__global__ __launch_bounds__(256, 4) void conv_kernel(
    const float* __restrict__ mu_in,
    const unsigned short* __restrict__ w_bf,
    const float* __restrict__ sp_in,
    float* __restrict__ mu_out,
    float* __restrict__ sig_out) {

    __shared__ __align__(16) unsigned short s_im[8 * 128 * 16];
    __shared__ __align__(16) float s_cs[8 * 128];
    __shared__ float s_ssn[4 * 128];
    __shared__ float s_sp[KN];

    const int bid = blockIdx.x;
    const int b = bid / NG;
    const int ho0 = (bid % NG) * 4;
    const int tid = threadIdx.x;
    const int lane = tid & 63;
    const int wid = tid >> 6;
    const int llo = lane & 15;
    const int lhi = lane >> 4;

    bfrag8 afr[4][3];
#pragma unroll
    for (int mt = 0; mt < 4; ++mt)
#pragma unroll
        for (int ks = 0; ks < 3; ++ks)
            afr[mt][ks] = *reinterpret_cast<const bfrag8*>(
                &w_bf[(mt * 16 + llo) * KP + ks * 32 + lhi * 8]);
    if (tid < KN) s_sp[tid] = sp_in[tid];

    {
        const int r = tid >> 5;
        const int c4 = (tid & 31) << 2;
        const float* p = mu_in + ((size_t)(b * 128 + ho0 + r) * 384 + c4 * 3);
        float4 f0 = reinterpret_cast<const float4*>(p)[0];
        float4 f1 = reinterpret_cast<const float4*>(p)[1];
        float4 f2 = reinterpret_cast<const float4*>(p)[2];
        float4 cs;
        cs.x = f0.x * f0.x + f0.y * f0.y + f0.z * f0.z;
        cs.y = f0.w * f0.w + f1.x * f1.x + f1.y * f1.y;
        cs.z = f1.z * f1.z + f1.w * f1.w + f2.x * f2.x;
        cs.w = f2.y * f2.y + f2.z * f2.z + f2.w * f2.w;
        *reinterpret_cast<float4*>(&s_cs[r * 128 + c4]) = cs;
    }
    {
        const int wo = wid + ((lane & 31) << 2);
        switch (wid) {
            case 0: im_fill<0>(mu_in, s_im, b, ho0, lane, wo); break;
            case 1: im_fill<3>(mu_in, s_im, b, ho0, lane, wo); break;
            case 2: im_fill<2>(mu_in, s_im, b, ho0, lane, wo); break;
            default: im_fill<1>(mu_in, s_im, b, ho0, lane, wo); break;
        }
    }
    __syncthreads();

    for (int i = tid; i < 512; i += 256) {
        const int hl = i >> 7, wo = i & 127;
        float v = 0.f;
        if (wo < HO) {
            float s = 0.f;
#pragma unroll
            for (int r = 0; r < 5; ++r)
#pragma unroll
                for (int d = 0; d < 5; ++d) s += s_cs[(hl + r) * 128 + wo + d];
            v = s * (1.0f / 75.0f);
        }
        s_ssn[hl * 128 + wo] = v;
    }
    __syncthreads();

    ffrag4 acc[2][4];
#pragma unroll
    for (int hl = 0; hl < 4; ++hl) {
#pragma unroll
        for (int nt = 0; nt < 2; ++nt)
#pragma unroll
            for (int mt = 0; mt < 4; ++mt)
                acc[nt][mt] = (ffrag4){0.f, 0.f, 0.f, 0.f};

#pragma unroll
        for (int nt = 0; nt < 2; ++nt) {
            const int wo = (wid * 2 + nt) * 16 + llo;
#pragma unroll
            for (int ks = 0; ks < 3; ++ks) {
                const int k0 = ks * 32 + lhi * 8;
                const int r = k0 >> 4;
                bfrag8 bfr = (bfrag8){0, 0, 0, 0, 0, 0, 0, 0};
                if (r < 5) {
                    bfr = *reinterpret_cast<const bfrag8*>(
                        (char*)s_im + im_off(hl + r, wo, (k0 & 15) >> 3));
                }
#pragma unroll
                for (int mt = 0; mt < 4; ++mt)
                    acc[nt][mt] = __builtin_amdgcn_mfma_f32_16x16x32_bf16(
                        afr[mt][ks], bfr, acc[nt][mt], 0, 0, 0);
            }
        }

        const size_t orow = (size_t)(b * HO + ho0 + hl) * (size_t)(HO * KN);
#pragma unroll
        for (int nt = 0; nt < 2; ++nt) {
            const int wo = (wid * 2 + nt) * 16 + llo;
            if (wo < HO) {
                const float ssn = s_ssn[hl * 128 + wo];
                const size_t obase = orow + (size_t)wo * KN;
#pragma unroll
                for (int mt = 0; mt < 4; ++mt) {
                    const int knb = mt * 16 + lhi * 4;
                    const float4 sp4 =
                        *reinterpret_cast<const float4*>(&s_sp[knb]);
                    *reinterpret_cast<float4*>(&mu_out[obase + knb]) =
                        make_float4(acc[nt][mt][0], acc[nt][mt][1],
                                    acc[nt][mt][2], acc[nt][mt][3]);
                    *reinterpret_cast<float4*>(&sig_out[obase + knb]) =
                        make_float4(sp4.x * ssn, sp4.y * ssn, sp4.z * ssn,
                                    sp4.w * ssn);
                }
            }
        }
    }
}

extern "C" void kernel_launch(void* const* d_in, const int* in_sizes, int n_in,
                              void* d_out, int out_size, void* d_ws,
                              size_t ws_size, hipStream_t stream) {
    const float* mu_in = (const float*)d_in[0];
    const float* w_mu = (const float*)d_in[1];
    const float* w_sigma = (const float*)d_in[2];
    float* out = (float*)d_out;

    float* mu_out = out;
    float* sig_out = out + NOUT;
    float* kl_out = out + 2 * NOUT;

    const bool big = ws_size >= WS_NEED;
    char* ws = (char*)d_ws;
    unsigned short* w_bf =
        (unsigned short*)(big ? ws + WS_WBF_OFF : ws);
    float* sp_ws = (float*)((big ? ws + WS_WBF_OFF : ws) + KN * KP * 2);

    prep_kernel<<<1, 256, 0, stream>>>(w_mu, w_sigma, w_bf, sp_ws);
    if (big) {
        uint4* X4 = (uint4*)(ws + WS_X_OFF);
        float* cs_ws = (float*)(ws + WS_CS_OFF);
        x_build_kernel<<<128 * 128, 256, 0, stream>>>(mu_in, X4, cs_ws);
        conv2_kernel<<<128 * NG, 256, 0, stream>>>(X4, cs_ws, w_bf, sp_ws,
                                                   mu_out, sig_out);
    } else {
        conv_kernel<<<128 * NG, 256, 0, stream>>>(mu_in, w_bf, sp_ws, mu_out,
                                                  sig_out);
    }
    kl_kernel<<<1, 64, 0, stream>>>(w_mu, w_sigma, kl_out);
}

// Round 6
// 228.523 us; speedup vs baseline: 1.5736x; 1.5736x over previous
//
#include <hip/hip_runtime.h>
#include <hip/hip_bf16.h>
#include <math.h>

#define KN 64
#define HO 124
#define KP 104
#define NOUT (128LL * 124 * 124 * 64)  // 125,960,192
#define NG 31                          // 124/4 ho-groups per image

// ws layout: ssn 7,872,512 B | w_bf 13,312 B | sp 256 B   (R5 proved ws >= 75 MB)
#define WS_SSN_OFF 0ULL
#define WS_WBF_OFF 7872512ULL
#define WS_SP_OFF 7885824ULL

typedef short bfrag8 __attribute__((ext_vector_type(8)));  // 8 bf16
typedef float ffrag4 __attribute__((ext_vector_type(4)));  // 4 f32

// round-to-nearest-even f32 -> bf16 bits (finite inputs)
__device__ __forceinline__ unsigned short f2bf(float f) {
    union { float f; unsigned u; } x;
    x.f = f;
    unsigned r = x.u + 0x7fffu + ((x.u >> 16) & 1u);
    return (unsigned short)(r >> 16);
}
__device__ __forceinline__ unsigned pack2(float a, float b) {
    return (unsigned)f2bf(a) | ((unsigned)f2bf(b) << 16);
}

// XOR-swizzled byte offset into s_im: [row][wo][16 bf16] = 32 B per (row,wo).
__device__ __forceinline__ int im_off(int row, int wo, int half) {
    return (((row * 128 + wo) * 32) + half * 16) ^ (((wo >> 2) & 7) << 4);
}

// ---------------- one-time prep: weight transpose->bf16 + softplus ---------
__global__ void prep_kernel(const float* __restrict__ w_mu,
                            const float* __restrict__ w_sigma,
                            unsigned short* __restrict__ w_bf,
                            float* __restrict__ sp_out) {
    const int tid = threadIdx.x;       // 256
    const int n = tid >> 2;            // 64 rows, 4 threads each
    const int kbase = (tid & 3) * 26;  // 4*26 = 104
#pragma unroll
    for (int kk = 0; kk < 26; ++kk) {
        const int k = kbase + kk;
        float v = 0.f;
        if (k < 80) {
            const int r = k >> 4, t = k & 15;
            if (t < 15) v = w_mu[(r * 15 + t) * KN + n];
        }
        w_bf[n * KP + k] = f2bf(v);
    }
    if (tid < KN) sp_out[tid] = log1pf(expf(w_sigma[tid]));
}

// ---------------- KL scalar kernel (one wave) ----------------
__global__ void kl_kernel(const float* __restrict__ w_mu,
                          const float* __restrict__ w_sigma,
                          float* __restrict__ out_kl) {
    int kn = threadIdx.x;  // 64 threads
    float s = 0.f;
#pragma unroll
    for (int i = 0; i < 75; ++i) {
        float m = w_mu[i * KN + kn];
        s = fmaf(m, m, s);
    }
    float lv = w_sigma[kn];
    float sp = log1pf(expf(lv));
    float val = 1.0f + lv - sp - s * (1.0f / 75.0f);
#pragma unroll
    for (int off = 32; off > 0; off >>= 1) val += __shfl_down(val, off);
    if (kn == 0) {
        float kl = -(val / 64.0f);
        if (isnan(kl) || isinf(kl)) kl = 1e-5f;
        out_kl[0] = kl;
    }
}

// ---------------- ssn prepass: patch sum-of-squares / 75 -------------------
// One block per (b, ho-group of 4). ssn_ws dense [b][ho][wo], 124 per row.
__global__ void ssn_kernel(const float* __restrict__ mu_in,
                           float* __restrict__ ssn_ws) {
    __shared__ __align__(16) float s_cs[8 * 128];
    const int bid = blockIdx.x;
    const int b = bid / NG;
    const int ho0 = (bid % NG) * 4;
    const int tid = threadIdx.x;

    {
        const int r = tid >> 5;          // 0..7
        const int c4 = (tid & 31) << 2;  // 0..124
        const float* p = mu_in + ((size_t)(b * 128 + ho0 + r) * 384 + c4 * 3);
        float4 f0 = reinterpret_cast<const float4*>(p)[0];
        float4 f1 = reinterpret_cast<const float4*>(p)[1];
        float4 f2 = reinterpret_cast<const float4*>(p)[2];
        float4 cs;
        cs.x = f0.x * f0.x + f0.y * f0.y + f0.z * f0.z;
        cs.y = f0.w * f0.w + f1.x * f1.x + f1.y * f1.y;
        cs.z = f1.z * f1.z + f1.w * f1.w + f2.x * f2.x;
        cs.w = f2.y * f2.y + f2.z * f2.z + f2.w * f2.w;
        *reinterpret_cast<float4*>(&s_cs[r * 128 + c4]) = cs;
    }
    __syncthreads();

#pragma unroll
    for (int it = 0; it < 2; ++it) {
        const int idx = tid + it * 256;
        const int hl = idx >> 7, wo = idx & 127;
        if (wo < HO) {
            float s = 0.f;
#pragma unroll
            for (int r = 0; r < 5; ++r) {
                const float* cr = &s_cs[(hl + r) * 128 + wo];
                s += cr[0] + cr[1] + cr[2] + cr[3] + cr[4];
            }
            ssn_ws[((size_t)(b * HO) + ho0 + hl) * HO + wo] = s * (1.0f / 75.0f);
        }
    }
}

// ---------------- sigma streaming kernel (fill-like) -----------------------
// chunk g (float4) -> pix p = g>>4, kn-quad q = g&15. Wave writes 1 KB
// contiguous. Plain stores (R5: nontemporal stores regressed badly).
__global__ __launch_bounds__(256) void sigma_kernel(
    const float* __restrict__ ssn_ws, const float* __restrict__ sp_in,
    float4* __restrict__ sig_out) {
    const long long TOT = 128LL * 124 * 124 * 16;  // 31,490,048 chunks
    const long long NT = (long long)gridDim.x * 256;
    const long long g0 = (long long)blockIdx.x * 256 + threadIdx.x;
    const float4 sp4 = reinterpret_cast<const float4*>(sp_in)[g0 & 15];

    long long g = g0;
    for (; g + 3 * NT < TOT; g += 4 * NT) {
        const float s0 = ssn_ws[g >> 4];
        const float s1 = ssn_ws[(g + NT) >> 4];
        const float s2 = ssn_ws[(g + 2 * NT) >> 4];
        const float s3 = ssn_ws[(g + 3 * NT) >> 4];
        sig_out[g] = make_float4(sp4.x * s0, sp4.y * s0, sp4.z * s0, sp4.w * s0);
        sig_out[g + NT] =
            make_float4(sp4.x * s1, sp4.y * s1, sp4.z * s1, sp4.w * s1);
        sig_out[g + 2 * NT] =
            make_float4(sp4.x * s2, sp4.y * s2, sp4.z * s2, sp4.w * s2);
        sig_out[g + 3 * NT] =
            make_float4(sp4.x * s3, sp4.y * s3, sp4.z * s3, sp4.w * s3);
    }
    for (; g < TOT; g += NT) {
        const float s = ssn_ws[g >> 4];
        sig_out[g] = make_float4(sp4.x * s, sp4.y * s, sp4.z * s, sp4.w * s);
    }
}

// im2col fill: wave-uniform alignment class. OFF = (3*wo) mod 4, constexpr.
template <int OFF>
__device__ __forceinline__ void im_fill(const float* __restrict__ mu_in,
                                        unsigned short* s_im, int b, int ho0,
                                        int lane, int wo) {
#pragma unroll
    for (int j = 0; j < 4; ++j) {
        const int row = ((lane >> 5) << 2) + j;  // 0..7
        uint4* dst0 =
            reinterpret_cast<uint4*>((char*)s_im + im_off(row, wo, 0));
        uint4* dst1 =
            reinterpret_cast<uint4*>((char*)s_im + im_off(row, wo, 1));
        if (wo >= 124) {
            *dst0 = make_uint4(0u, 0u, 0u, 0u);
            *dst1 = make_uint4(0u, 0u, 0u, 0u);
            continue;
        }
        const float* p =
            mu_in + ((size_t)(b * 128 + ho0 + row) * 384 + wo * 3 - OFF);
        float w[20];
        float4 f;
        f = reinterpret_cast<const float4*>(p)[0];
        w[0] = f.x; w[1] = f.y; w[2] = f.z; w[3] = f.w;
        f = reinterpret_cast<const float4*>(p)[1];
        w[4] = f.x; w[5] = f.y; w[6] = f.z; w[7] = f.w;
        f = reinterpret_cast<const float4*>(p)[2];
        w[8] = f.x; w[9] = f.y; w[10] = f.z; w[11] = f.w;
        f = reinterpret_cast<const float4*>(p)[3];
        w[12] = f.x; w[13] = f.y; w[14] = f.z; w[15] = f.w;
        if (OFF >= 2) {
            f = reinterpret_cast<const float4*>(p)[4];
            w[16] = f.x; w[17] = f.y; w[18] = f.z; w[19] = f.w;
        } else {
            w[16] = 0.f; w[17] = 0.f; w[18] = 0.f; w[19] = 0.f;
        }
        unsigned u0 = pack2(w[OFF + 0], w[OFF + 1]);
        unsigned u1 = pack2(w[OFF + 2], w[OFF + 3]);
        unsigned u2 = pack2(w[OFF + 4], w[OFF + 5]);
        unsigned u3 = pack2(w[OFF + 6], w[OFF + 7]);
        unsigned u4 = pack2(w[OFF + 8], w[OFF + 9]);
        unsigned u5 = pack2(w[OFF + 10], w[OFF + 11]);
        unsigned u6 = pack2(w[OFF + 12], w[OFF + 13]);
        unsigned u7 = pack2(w[OFF + 14], 0.0f);  // t=15: weight is zero
        *dst0 = make_uint4(u0, u1, u2, u3);
        *dst1 = make_uint4(u4, u5, u6, u7);
    }
}

// ---------------- conv kernel: mu ONLY (single output stream) --------------
__global__ __launch_bounds__(256, 4) void conv_mu_kernel(
    const float* __restrict__ mu_in,
    const unsigned short* __restrict__ w_bf,
    float* __restrict__ mu_out) {

    __shared__ __align__(16) unsigned short s_im[8 * 128 * 16];  // 32 KB

    const int bid = blockIdx.x;
    const int b = bid / NG;
    const int ho0 = (bid % NG) * 4;
    const int tid = threadIdx.x;
    const int lane = tid & 63;
    const int wid = tid >> 6;
    const int llo = lane & 15;
    const int lhi = lane >> 4;

    // weights -> regs (L2-hot)
    bfrag8 afr[4][3];
#pragma unroll
    for (int mt = 0; mt < 4; ++mt)
#pragma unroll
        for (int ks = 0; ks < 3; ++ks)
            afr[mt][ks] = *reinterpret_cast<const bfrag8*>(
                &w_bf[(mt * 16 + llo) * KP + ks * 32 + lhi * 8]);

    // im2col (each wave owns one wo mod-4 class)
    {
        const int wo = wid + ((lane & 31) << 2);
        switch (wid) {  // OFF = (3*class) mod 4
            case 0: im_fill<0>(mu_in, s_im, b, ho0, lane, wo); break;
            case 1: im_fill<3>(mu_in, s_im, b, ho0, lane, wo); break;
            case 2: im_fill<2>(mu_in, s_im, b, ho0, lane, wo); break;
            default: im_fill<1>(mu_in, s_im, b, ho0, lane, wo); break;
        }
    }
    __syncthreads();

#pragma unroll
    for (int hl = 0; hl < 4; ++hl) {
        ffrag4 acc[2][4];
#pragma unroll
        for (int nt = 0; nt < 2; ++nt)
#pragma unroll
            for (int mt = 0; mt < 4; ++mt)
                acc[nt][mt] = (ffrag4){0.f, 0.f, 0.f, 0.f};

#pragma unroll
        for (int nt = 0; nt < 2; ++nt) {
            const int wo = (wid * 2 + nt) * 16 + llo;
#pragma unroll
            for (int ks = 0; ks < 3; ++ks) {
                const int k0 = ks * 32 + lhi * 8;
                const int r = k0 >> 4;  // 0..5 (5 => k>=80: zero operand)
                bfrag8 bfr = (bfrag8){0, 0, 0, 0, 0, 0, 0, 0};
                if (r < 5) {
                    bfr = *reinterpret_cast<const bfrag8*>(
                        (char*)s_im + im_off(hl + r, wo, (k0 & 15) >> 3));
                }
#pragma unroll
                for (int mt = 0; mt < 4; ++mt)
                    acc[nt][mt] = __builtin_amdgcn_mfma_f32_16x16x32_bf16(
                        afr[mt][ks], bfr, acc[nt][mt], 0, 0, 0);
            }
        }

        const size_t orow = (size_t)(b * HO + ho0 + hl) * (size_t)(HO * KN);
#pragma unroll
        for (int nt = 0; nt < 2; ++nt) {
            const int wo = (wid * 2 + nt) * 16 + llo;
            if (wo < HO) {
                const size_t obase = orow + (size_t)wo * KN;
#pragma unroll
                for (int mt = 0; mt < 4; ++mt) {
                    const int knb = mt * 16 + lhi * 4;
                    *reinterpret_cast<float4*>(&mu_out[obase + knb]) =
                        make_float4(acc[nt][mt][0], acc[nt][mt][1],
                                    acc[nt][mt][2], acc[nt][mt][3]);
                }
            }
        }
    }
}

extern "C" void kernel_launch(void* const* d_in, const int* in_sizes, int n_in,
                              void* d_out, int out_size, void* d_ws,
                              size_t ws_size, hipStream_t stream) {
    const float* mu_in = (const float*)d_in[0];
    const float* w_mu = (const float*)d_in[1];
    const float* w_sigma = (const float*)d_in[2];
    float* out = (float*)d_out;

    float* mu_out = out;             // N floats
    float* sig_out = out + NOUT;     // N floats
    float* kl_out = out + 2 * NOUT;  // 1 float

    char* ws = (char*)d_ws;
    float* ssn_ws = (float*)(ws + WS_SSN_OFF);
    unsigned short* w_bf = (unsigned short*)(ws + WS_WBF_OFF);
    float* sp_ws = (float*)(ws + WS_SP_OFF);

    prep_kernel<<<1, 256, 0, stream>>>(w_mu, w_sigma, w_bf, sp_ws);
    ssn_kernel<<<128 * NG, 256, 0, stream>>>(mu_in, ssn_ws);
    conv_mu_kernel<<<128 * NG, 256, 0, stream>>>(mu_in, w_bf, mu_out);
    sigma_kernel<<<2048, 256, 0, stream>>>(ssn_ws, sp_ws,
                                           (float4*)sig_out);
    kl_kernel<<<1, 64, 0, stream>>>(w_mu, w_sigma, kl_out);
}